// Round 1
// baseline (254.894 us; speedup 1.0000x reference)
//
#include <hip/hip_runtime.h>
#include <stdint.h>
#include <stddef.h>

#define DEVI __device__ __forceinline__

typedef __bf16 bf16x8 __attribute__((ext_vector_type(8)));
typedef float  f32x4  __attribute__((ext_vector_type(4)));
typedef unsigned short u16;
typedef u16 u16x8 __attribute__((ext_vector_type(8)));
typedef u16 u16x4 __attribute__((ext_vector_type(4)));

typedef __attribute__((address_space(1))) void as1_void;
typedef __attribute__((address_space(3))) void as3_void;

static constexpr float LOG2E = 1.4426950408889634f;

DEVI u16 f2bf(float f) {
  uint32_t u = __builtin_bit_cast(uint32_t, f);
  u += 0x7fffu + ((u >> 16) & 1u);
  return (u16)(u >> 16);
}

DEVI void gload_lds16(const void* g, void* l) {
  __builtin_amdgcn_global_load_lds((as1_void*)(void*)g, (as3_void*)l, 16, 0, 0);
}

#if __has_builtin(__builtin_amdgcn_exp2f)
DEVI float fast_exp2(float x) { return __builtin_amdgcn_exp2f(x); }
#else
DEVI float fast_exp2(float x) { return exp2f(x); }
#endif

// ---------------- elementwise fp32 -> bf16 ----------------
__global__ __launch_bounds__(256) void k_cvt(const float* __restrict__ in,
                                             u16* __restrict__ out, int n) {
  int i = (blockIdx.x * 256 + threadIdx.x) * 4;
  if (i >= n) return;
  const float4 v = *(const float4*)(in + i);
  u16x4 o = { f2bf(v.x), f2bf(v.y), f2bf(v.z), f2bf(v.w) };
  *(u16x4*)(out + i) = o;
}

// ------------- transpose + convert: in fp32 [R][C] -> out bf16 [C][R] -------------
__global__ __launch_bounds__(256) void k_tcvt(const float* __restrict__ in,
                                              u16* __restrict__ out, int R, int C) {
  __shared__ float tile[32][33];
  const int c0 = blockIdx.x * 32, r0 = blockIdx.y * 32;
  const int tx = threadIdx.x, ty = threadIdx.y;
#pragma unroll
  for (int i = ty; i < 32; i += 8)
    tile[i][tx] = in[(size_t)(r0 + i) * C + (c0 + tx)];
  __syncthreads();
#pragma unroll
  for (int i = ty; i < 32; i += 8)
    out[(size_t)(c0 + i) * R + (r0 + tx)] = f2bf(tile[tx][i]);
}

// ---------------- GEMM: C[M][N] = A[M][K] * Bt[N][K]^T  (bf16 in, fp32 acc) ----------------
// EPI 0: qkv epilogue (split q/k/v into [B,H,S,d] bf16 ws + present fp32)
// EPI 1: proj epilogue (fp32 out + bias)
template <int EPI>
__global__ __launch_bounds__(256) void k_gemm(
    const u16* __restrict__ A, const u16* __restrict__ Bt,
    const float* __restrict__ bias,
    u16* __restrict__ wq, u16* __restrict__ wk, u16* __restrict__ wv,
    float* __restrict__ pk, float* __restrict__ pv, float* __restrict__ of) {
  constexpr int K = 1024;
  __shared__ __align__(16) u16 Ash[128 * 32];
  __shared__ __align__(16) u16 Bsh[128 * 32];
  const int tid = threadIdx.x;
  const int lane = tid & 63, wid = tid >> 6;
  const int wm = wid >> 1, wn = wid & 1;
  const int lr = lane & 15, lg = lane >> 4;
  const int m0 = blockIdx.y * 128, n0 = blockIdx.x * 128;

  const int c = wid * 64 + lane;  // 16B chunk id, 0..255
  const u16* Ag1 = A + (size_t)(m0 + (c >> 2)) * K + (c & 3) * 8;
  const u16* Ag2 = A + (size_t)(m0 + 64 + (c >> 2)) * K + (c & 3) * 8;
  const u16* Bg1 = Bt + (size_t)(n0 + (c >> 2)) * K + (c & 3) * 8;
  const u16* Bg2 = Bt + (size_t)(n0 + 64 + (c >> 2)) * K + (c & 3) * 8;
  u16* Ad1 = Ash + wid * 512;
  u16* Ad2 = Ash + 2048 + wid * 512;
  u16* Bd1 = Bsh + wid * 512;
  u16* Bd2 = Bsh + 2048 + wid * 512;

  f32x4 acc[4][4];
#pragma unroll
  for (int i = 0; i < 4; ++i)
#pragma unroll
    for (int j = 0; j < 4; ++j) acc[i][j] = (f32x4)0.0f;

  for (int k0 = 0; k0 < K; k0 += 32) {
    gload_lds16(Ag1 + k0, Ad1);
    gload_lds16(Ag2 + k0, Ad2);
    gload_lds16(Bg1 + k0, Bd1);
    gload_lds16(Bg2 + k0, Bd2);
    __syncthreads();
    bf16x8 af[4], bfr[4];
#pragma unroll
    for (int f = 0; f < 4; ++f) {
      af[f]  = *(const bf16x8*)&Ash[(wm * 64 + f * 16 + lr) * 32 + lg * 8];
      bfr[f] = *(const bf16x8*)&Bsh[(wn * 64 + f * 16 + lr) * 32 + lg * 8];
    }
#pragma unroll
    for (int i = 0; i < 4; ++i)
#pragma unroll
      for (int j = 0; j < 4; ++j)
        acc[i][j] = __builtin_amdgcn_mfma_f32_16x16x32_bf16(af[i], bfr[j], acc[i][j], 0, 0, 0);
    __syncthreads();
  }

  if constexpr (EPI == 0) {
#pragma unroll
    for (int j = 0; j < 4; ++j) {
      const int n = n0 + wn * 64 + j * 16 + lr;
      const float bv = bias[n];
      const int sec = n >> 10;
      const int nn = n & 1023;
      const int h = nn >> 6, dd = nn & 63;
#pragma unroll
      for (int i = 0; i < 4; ++i) {
        const int mb = m0 + wm * 64 + i * 16 + lg * 4;
#pragma unroll
        for (int r = 0; r < 4; ++r) {
          const int m = mb + r;
          const float v = acc[i][j][r] + bv;
          const int b = m >> 11, s = m & 2047;
          const size_t idx = (size_t)(b * 16 + h) * 131072 + (size_t)s * 64 + dd;
          if (sec == 0) {
            wq[idx] = f2bf(v);
          } else if (sec == 1) {
            wk[idx] = f2bf(v);
            pk[idx] = v;
          } else {
            wv[idx] = f2bf(v);
            pv[idx] = v;
          }
        }
      }
    }
  } else {
#pragma unroll
    for (int j = 0; j < 4; ++j) {
      const int n = n0 + wn * 64 + j * 16 + lr;
      const float bv = bias[n];
#pragma unroll
      for (int i = 0; i < 4; ++i) {
        const int mb = m0 + wm * 64 + i * 16 + lg * 4;
#pragma unroll
        for (int r = 0; r < 4; ++r)
          of[(size_t)(mb + r) * 1024 + n] = acc[i][j][r] + bv;
      }
    }
  }
}

// ---------------- causal flash attention ----------------
// grid (qt=S/64, bh=B*H); 256 threads = 4 waves, each wave owns 16 q-rows.
__global__ __launch_bounds__(256) void k_attn(const u16* __restrict__ Q,
                                              const u16* __restrict__ Kw,
                                              const u16* __restrict__ Vw,
                                              u16* __restrict__ Aout) {
  __shared__ __align__(16) u16 Ksh[64 * 64];   // [kpos][dd], XOR-swizzled rows
  __shared__ __align__(16) u16 Vsh[64 * 64];   // [dd][kpos] (transposed), swizzled
  __shared__ __align__(16) u16 Psh[4 * 16 * 64];  // per-wave [16 q][64 k], swizzled
  const int tid = threadIdx.x;
  const int lane = tid & 63, w = tid >> 6;
  const int lr = lane & 15, lg = lane >> 4;
  const int qt = blockIdx.x, bh = blockIdx.y;
  const size_t hb = (size_t)bh * (2048 * 64);

  const int qrow = qt * 64 + w * 16 + lr;
  const bf16x8 aq0 = *(const bf16x8*)(Q + hb + (size_t)qrow * 64 + lg * 8);
  const bf16x8 aq1 = *(const bf16x8*)(Q + hb + (size_t)qrow * 64 + 32 + lg * 8);

  f32x4 o[4];
#pragma unroll
  for (int dc = 0; dc < 4; ++dc) o[dc] = (f32x4)0.0f;
  float mrun[4], lrun[4];
#pragma unroll
  for (int r = 0; r < 4; ++r) { mrun[r] = -1e30f; lrun[r] = 0.0f; }

  char* KshB = (char*)Ksh;
  char* VshB = (char*)Vsh;
  char* PshB = (char*)Psh + w * 2048;

  for (int jt = 0; jt <= qt; ++jt) {
    // ---- stage K [kpos][dd] and V^T [dd][kpos] ----
#pragma unroll
    for (int it = 0; it < 2; ++it) {
      const int cc = tid + it * 256;
      const int row = cc >> 3, slot = cc & 7;
      const size_t gsrc = hb + (size_t)(jt * 64 + row) * 64 + slot * 8;
      u16x8 kv = *(const u16x8*)(Kw + gsrc);
      *(u16x8*)(KshB + row * 128 + ((slot * 16) ^ ((row & 7) << 4))) = kv;
      u16x8 vv = *(const u16x8*)(Vw + gsrc);
#pragma unroll
      for (int jj = 0; jj < 8; ++jj) {
        const int dd = slot * 8 + jj;
        *(u16*)(VshB + dd * 128 + ((row * 2) ^ (jj << 4))) = vv[jj];
      }
    }
    __syncthreads();

    // ---- S = Q K^T ----
    f32x4 sf[4];
#pragma unroll
    for (int kf = 0; kf < 4; ++kf) {
      const int krow = kf * 16 + lr;
      const int sw = (krow & 7) << 4;
      const bf16x8 b0 = *(const bf16x8*)(KshB + krow * 128 + ((lg * 16) ^ sw));
      const bf16x8 b1 = *(const bf16x8*)(KshB + krow * 128 + ((lg * 16 + 64) ^ sw));
      f32x4 z = (f32x4)0.0f;
      z = __builtin_amdgcn_mfma_f32_16x16x32_bf16(aq0, b0, z, 0, 0, 0);
      z = __builtin_amdgcn_mfma_f32_16x16x32_bf16(aq1, b1, z, 0, 0, 0);
      sf[kf] = z;
    }

    // ---- online softmax (per q-row; row = lg*4+r, cols across lr + kf) ----
#pragma unroll
    for (int r = 0; r < 4; ++r) {
      const int ig = qt * 64 + w * 16 + lg * 4 + r;
      float mx = -1e30f;
#pragma unroll
      for (int kf = 0; kf < 4; ++kf) {
        const int jg = jt * 64 + kf * 16 + lr;
        float v = sf[kf][r] * 0.125f;
        v = (jg <= ig) ? v : -1e30f;
        sf[kf][r] = v;
        mx = fmaxf(mx, v);
      }
      mx = fmaxf(mx, __shfl_xor(mx, 1));
      mx = fmaxf(mx, __shfl_xor(mx, 2));
      mx = fmaxf(mx, __shfl_xor(mx, 4));
      mx = fmaxf(mx, __shfl_xor(mx, 8));
      const float mnew = fmaxf(mrun[r], mx);
      const float alpha = fast_exp2((mrun[r] - mnew) * LOG2E);
      mrun[r] = mnew;
      float rs = 0.0f;
#pragma unroll
      for (int kf = 0; kf < 4; ++kf) {
        const float p = fast_exp2((sf[kf][r] - mnew) * LOG2E);
        sf[kf][r] = p;
        rs += p;
      }
      rs += __shfl_xor(rs, 1);
      rs += __shfl_xor(rs, 2);
      rs += __shfl_xor(rs, 4);
      rs += __shfl_xor(rs, 8);
      lrun[r] = lrun[r] * alpha + rs;
#pragma unroll
      for (int dc = 0; dc < 4; ++dc) o[dc][r] *= alpha;
    }

    // ---- P -> LDS (bf16), re-read as A-fragments ----
#pragma unroll
    for (int kf = 0; kf < 4; ++kf)
#pragma unroll
      for (int r = 0; r < 4; ++r) {
        const int prow = lg * 4 + r;
        const int pcol = kf * 16 + lr;
        *(u16*)(PshB + prow * 128 + ((pcol * 2) ^ ((prow & 7) << 4))) = f2bf(sf[kf][r]);
      }

    const int asw = (lr & 7) << 4;
    const bf16x8 pa0 = *(const bf16x8*)(PshB + lr * 128 + ((lg * 16) ^ asw));
    const bf16x8 pa1 = *(const bf16x8*)(PshB + lr * 128 + ((lg * 16 + 64) ^ asw));
#pragma unroll
    for (int dc = 0; dc < 4; ++dc) {
      const int vrow = dc * 16 + lr;
      const int vsw = (vrow & 7) << 4;
      const bf16x8 v0 = *(const bf16x8*)(VshB + vrow * 128 + ((lg * 16) ^ vsw));
      const bf16x8 v1 = *(const bf16x8*)(VshB + vrow * 128 + ((lg * 16 + 64) ^ vsw));
      o[dc] = __builtin_amdgcn_mfma_f32_16x16x32_bf16(pa0, v0, o[dc], 0, 0, 0);
      o[dc] = __builtin_amdgcn_mfma_f32_16x16x32_bf16(pa1, v1, o[dc], 0, 0, 0);
    }
    __syncthreads();
  }

  // ---- normalize + store merged-head row ----
  const int b = bh >> 4, h = bh & 15;
#pragma unroll
  for (int r = 0; r < 4; ++r) {
    const float inv = 1.0f / lrun[r];
    const int srow = qt * 64 + w * 16 + lg * 4 + r;
    u16* orow = Aout + (size_t)(b * 2048 + srow) * 1024 + h * 64;
#pragma unroll
    for (int dc = 0; dc < 4; ++dc)
      orow[dc * 16 + lr] = f2bf(o[dc][r] * inv);
  }
}

extern "C" void kernel_launch(void* const* d_in, const int* in_sizes, int n_in,
                              void* d_out, int out_size, void* d_ws, size_t ws_size,
                              hipStream_t stream) {
  const float* x      = (const float*)d_in[0];
  const float* w_attn = (const float*)d_in[1];
  const float* b_attn = (const float*)d_in[2];
  const float* w_proj = (const float*)d_in[3];
  const float* b_proj = (const float*)d_in[4];
  float* out = (float*)d_out;

  char* ws = (char*)d_ws;
  u16* x_bf  = (u16*)(ws);                    // [4096][1024] bf16   (8 MB)
  u16* wat_t = (u16*)(ws + 8388608);          // [3072][1024] bf16   (6 MB)
  u16* wpj_t = (u16*)(ws + 14680064);         // [1024][1024] bf16   (2 MB)
  u16* q_ws  = (u16*)(ws + 16777216);         // [B,H,S,d] bf16      (8 MB)
  u16* k_ws  = (u16*)(ws + 25165824);         // [B,H,S,d] bf16      (8 MB)
  u16* v_ws  = (u16*)(ws + 33554432);         // [B,H,S,d] bf16      (8 MB)
  u16* a_ws  = (u16*)(ws + 41943040);         // [B,S,nx]  bf16      (8 MB)

  k_cvt<<<4096, 256, 0, stream>>>(x, x_bf, 4194304);
  k_tcvt<<<dim3(96, 32), dim3(32, 8), 0, stream>>>(w_attn, wat_t, 1024, 3072);
  k_tcvt<<<dim3(32, 32), dim3(32, 8), 0, stream>>>(w_proj, wpj_t, 1024, 1024);

  k_gemm<0><<<dim3(24, 32), 256, 0, stream>>>(x_bf, wat_t, b_attn,
                                              q_ws, k_ws, v_ws,
                                              out + 4194304, out + 8388608, nullptr);

  k_attn<<<dim3(32, 32), 256, 0, stream>>>(q_ws, k_ws, v_ws, a_ws);

  k_gemm<1><<<dim3(8, 32), 256, 0, stream>>>(a_ws, wpj_t, b_proj,
                                             nullptr, nullptr, nullptr,
                                             nullptr, nullptr, out);
}

// Round 2
// 161.999 us; speedup vs baseline: 1.5734x; 1.5734x over previous
//
#include <hip/hip_runtime.h>
#include <stdint.h>
#include <stddef.h>

#define DEVI __device__ __forceinline__

typedef __bf16 bf16x8 __attribute__((ext_vector_type(8)));
typedef float  f32x4  __attribute__((ext_vector_type(4)));
typedef float  f32x16 __attribute__((ext_vector_type(16)));
typedef unsigned short u16;
typedef uint32_t u32;
typedef u16 u16x8 __attribute__((ext_vector_type(8)));
typedef u16 u16x4 __attribute__((ext_vector_type(4)));
typedef u32 u32x2 __attribute__((ext_vector_type(2)));
typedef u32 u32x4 __attribute__((ext_vector_type(4)));

typedef __attribute__((address_space(1))) void as1_void;
typedef __attribute__((address_space(3))) void as3_void;

static constexpr float SC = 0.18033688011112042f;  // (1/8) * log2(e)

DEVI u16 f2bf(float f) {
  uint32_t u = __builtin_bit_cast(uint32_t, f);
  u += 0x7fffu + ((u >> 16) & 1u);
  return (u16)(u >> 16);
}

DEVI void gload_lds16(const void* g, void* l) {
  __builtin_amdgcn_global_load_lds((as1_void*)(void*)g, (as3_void*)l, 16, 0, 0);
}

#if __has_builtin(__builtin_amdgcn_exp2f)
DEVI float fast_exp2(float x) { return __builtin_amdgcn_exp2f(x); }
#else
DEVI float fast_exp2(float x) { return exp2f(x); }
#endif

DEVI u32 cvtpk(float lo, float hi) {
  u32 r;
  asm("v_cvt_pk_bf16_f32 %0, %1, %2" : "=v"(r) : "v"(lo), "v"(hi));
  return r;
}
DEVI void plswap(u32& a, u32& b) {
  asm("v_permlane32_swap_b32 %0, %1" : "+v"(a), "+v"(b));
}

// ---------------- elementwise fp32 -> bf16 ----------------
__global__ __launch_bounds__(256) void k_cvt(const float* __restrict__ in,
                                             u16* __restrict__ out, int n) {
  int i = (blockIdx.x * 256 + threadIdx.x) * 4;
  if (i >= n) return;
  const float4 v = *(const float4*)(in + i);
  u16x4 o = { f2bf(v.x), f2bf(v.y), f2bf(v.z), f2bf(v.w) };
  *(u16x4*)(out + i) = o;
}

// ------------- transpose + convert: in fp32 [R][C] -> out bf16 [C][R] -------------
__global__ __launch_bounds__(256) void k_tcvt(const float* __restrict__ in,
                                              u16* __restrict__ out, int R, int C) {
  __shared__ float tile[32][33];
  const int c0 = blockIdx.x * 32, r0 = blockIdx.y * 32;
  const int tx = threadIdx.x, ty = threadIdx.y;
#pragma unroll
  for (int i = ty; i < 32; i += 8)
    tile[i][tx] = in[(size_t)(r0 + i) * C + (c0 + tx)];
  __syncthreads();
#pragma unroll
  for (int i = ty; i < 32; i += 8)
    out[(size_t)(c0 + i) * R + (r0 + tx)] = f2bf(tile[tx][i]);
}

// ---------------- GEMM: C[M][N] = A[M][K] * Bt[N][K]^T  (bf16 in, fp32 acc) ----------------
// EPI 0: qkv epilogue (q,k bf16 [B,H,S,d]; v -> vT bf16 [B,H,d,S]; present fp32)
// EPI 1: proj epilogue (fp32 out + bias)
template <int EPI>
__global__ __launch_bounds__(256) void k_gemm(
    const u16* __restrict__ A, const u16* __restrict__ Bt,
    const float* __restrict__ bias,
    u16* __restrict__ wq, u16* __restrict__ wk, u16* __restrict__ vt,
    float* __restrict__ pk, float* __restrict__ pv, float* __restrict__ of) {
  constexpr int K = 1024;
  __shared__ __align__(16) u16 Ash[128 * 32];
  __shared__ __align__(16) u16 Bsh[128 * 32];
  const int tid = threadIdx.x;
  const int lane = tid & 63, wid = tid >> 6;
  const int wm = wid >> 1, wn = wid & 1;
  const int lr = lane & 15, lg = lane >> 4;
  const int m0 = blockIdx.y * 128, n0 = blockIdx.x * 128;

  const int c = wid * 64 + lane;  // 16B chunk id, 0..255
  const u16* Ag1 = A + (size_t)(m0 + (c >> 2)) * K + (c & 3) * 8;
  const u16* Ag2 = A + (size_t)(m0 + 64 + (c >> 2)) * K + (c & 3) * 8;
  const u16* Bg1 = Bt + (size_t)(n0 + (c >> 2)) * K + (c & 3) * 8;
  const u16* Bg2 = Bt + (size_t)(n0 + 64 + (c >> 2)) * K + (c & 3) * 8;
  u16* Ad1 = Ash + wid * 512;
  u16* Ad2 = Ash + 2048 + wid * 512;
  u16* Bd1 = Bsh + wid * 512;
  u16* Bd2 = Bsh + 2048 + wid * 512;

  f32x4 acc[4][4];
#pragma unroll
  for (int i = 0; i < 4; ++i)
#pragma unroll
    for (int j = 0; j < 4; ++j) acc[i][j] = (f32x4)0.0f;

  for (int k0 = 0; k0 < K; k0 += 32) {
    gload_lds16(Ag1 + k0, Ad1);
    gload_lds16(Ag2 + k0, Ad2);
    gload_lds16(Bg1 + k0, Bd1);
    gload_lds16(Bg2 + k0, Bd2);
    __syncthreads();
    bf16x8 af[4], bfr[4];
#pragma unroll
    for (int f = 0; f < 4; ++f) {
      af[f]  = *(const bf16x8*)&Ash[(wm * 64 + f * 16 + lr) * 32 + lg * 8];
      bfr[f] = *(const bf16x8*)&Bsh[(wn * 64 + f * 16 + lr) * 32 + lg * 8];
    }
#pragma unroll
    for (int i = 0; i < 4; ++i)
#pragma unroll
      for (int j = 0; j < 4; ++j)
        acc[i][j] = __builtin_amdgcn_mfma_f32_16x16x32_bf16(af[i], bfr[j], acc[i][j], 0, 0, 0);
    __syncthreads();
  }

  if constexpr (EPI == 0) {
#pragma unroll
    for (int j = 0; j < 4; ++j) {
      const int n = n0 + wn * 64 + j * 16 + lr;
      const float bv = bias[n];
      const int sec = n >> 10;
      const int nn = n & 1023;
      const int h = nn >> 6, dd = nn & 63;
#pragma unroll
      for (int i = 0; i < 4; ++i) {
        const int mb = m0 + wm * 64 + i * 16 + lg * 4;
        const int bb = mb >> 11, ss = mb & 2047;
        const size_t ib = (size_t)(bb * 16 + h) * 131072 + (size_t)ss * 64 + dd;
        if (sec == 0) {
#pragma unroll
          for (int r = 0; r < 4; ++r)
            wq[ib + (size_t)r * 64] = f2bf(acc[i][j][r] + bv);
        } else if (sec == 1) {
#pragma unroll
          for (int r = 0; r < 4; ++r) {
            const float v = acc[i][j][r] + bv;
            wk[ib + (size_t)r * 64] = f2bf(v);
            pk[ib + (size_t)r * 64] = v;
          }
        } else {
          u16x4 vv;
#pragma unroll
          for (int r = 0; r < 4; ++r) {
            const float v = acc[i][j][r] + bv;
            pv[ib + (size_t)r * 64] = v;
            vv[r] = f2bf(v);
          }
          *(u16x4*)(vt + ((size_t)(bb * 16 + h) * 64 + dd) * 2048 + ss) = vv;
        }
      }
    }
  } else {
#pragma unroll
    for (int j = 0; j < 4; ++j) {
      const int n = n0 + wn * 64 + j * 16 + lr;
      const float bv = bias[n];
#pragma unroll
      for (int i = 0; i < 4; ++i) {
        const int mb = m0 + wm * 64 + i * 16 + lg * 4;
#pragma unroll
        for (int r = 0; r < 4; ++r)
          of[(size_t)(mb + r) * 1024 + n] = acc[i][j][r] + bv;
      }
    }
  }
}

// ---------------- causal flash attention, swapped-QK^T, no LDS ----------------
// 256 blocks x 256 thr; wave = 1 work unit; wave handles q-tiles (pair, 63-pair)
// of 32 rows each -> uniform 33 KV-iters. S^T = mfma(K, Q): lane&31 = q column.
__global__ __launch_bounds__(256, 1) void k_attn(const u16* __restrict__ Q,
                                                 const u16* __restrict__ Kp,
                                                 const u16* __restrict__ VT,
                                                 u16* __restrict__ AO) {
  const int tid = threadIdx.x;
  const int lane = tid & 63, w = tid >> 6;
  const int l31 = lane & 31, hi = lane >> 5;
  const int bh = blockIdx.x & 31;          // bid%8 == bh%8 -> each bh pinned to one XCD's L2
  const int qc = blockIdx.x >> 5;
  const int pair = qc * 4 + w;             // 0..31
  const int b = bh >> 4, h = bh & 15;
  const size_t hb = (size_t)bh * (2048 * 64);

  const u16* Kbase = Kp + hb + (size_t)l31 * 64 + hi * 8;    // + (jt*64+sub*32)*64 + c*16
  const u16* Vbase = VT + hb + (size_t)l31 * 2048 + hi * 8;  // + mt*32*2048 + jt*64 + c*16
  const u16* Qbase = Q  + hb + (size_t)l31 * 64 + hi * 8;    // + qb*64 + c*16

  for (int t = 0; t < 2; ++t) {
    const int qt = (t == 0) ? pair : (63 - pair);
    const int qb = qt * 32;
    const int jtmax = qt >> 1;

    bf16x8 qf0 = *(const bf16x8*)(Qbase + (size_t)qb * 64);
    bf16x8 qf1 = *(const bf16x8*)(Qbase + (size_t)qb * 64 + 16);
    bf16x8 qf2 = *(const bf16x8*)(Qbase + (size_t)qb * 64 + 32);
    bf16x8 qf3 = *(const bf16x8*)(Qbase + (size_t)qb * 64 + 48);

    f32x16 o0 = (f32x16)0.0f, o1 = (f32x16)0.0f;
    float mrun = -1e30f, lrun = 0.0f;

    bf16x8 kf[2][4];
#pragma unroll
    for (int s = 0; s < 2; ++s)
#pragma unroll
      for (int c = 0; c < 4; ++c)
        kf[s][c] = *(const bf16x8*)(Kbase + (size_t)(s * 32) * 64 + c * 16);

    for (int jt = 0; jt <= jtmax; ++jt) {
      const bool last = (jt == jtmax);
      // V^T fragments for this KV tile (used at the end -> latency hidden)
      bf16x8 vf[2][4];
#pragma unroll
      for (int mt = 0; mt < 2; ++mt)
#pragma unroll
        for (int c = 0; c < 4; ++c)
          vf[mt][c] = *(const bf16x8*)(Vbase + (size_t)(mt * 32) * 2048 + jt * 64 + c * 16);

      // S^T[kpos][q] = K . Q^T
      f32x16 s0 = (f32x16)0.0f, s1 = (f32x16)0.0f;
      s0 = __builtin_amdgcn_mfma_f32_32x32x16_bf16(kf[0][0], qf0, s0, 0, 0, 0);
      s1 = __builtin_amdgcn_mfma_f32_32x32x16_bf16(kf[1][0], qf0, s1, 0, 0, 0);
      s0 = __builtin_amdgcn_mfma_f32_32x32x16_bf16(kf[0][1], qf1, s0, 0, 0, 0);
      s1 = __builtin_amdgcn_mfma_f32_32x32x16_bf16(kf[1][1], qf1, s1, 0, 0, 0);
      s0 = __builtin_amdgcn_mfma_f32_32x32x16_bf16(kf[0][2], qf2, s0, 0, 0, 0);
      s1 = __builtin_amdgcn_mfma_f32_32x32x16_bf16(kf[1][2], qf2, s1, 0, 0, 0);
      s0 = __builtin_amdgcn_mfma_f32_32x32x16_bf16(kf[0][3], qf3, s0, 0, 0, 0);
      s1 = __builtin_amdgcn_mfma_f32_32x32x16_bf16(kf[1][3], qf3, s1, 0, 0, 0);

      // prefetch next K tile under the softmax
      if (!last) {
#pragma unroll
        for (int s = 0; s < 2; ++s)
#pragma unroll
          for (int c = 0; c < 4; ++c)
            kf[s][c] = *(const bf16x8*)(Kbase + (size_t)((jt + 1) * 64 + s * 32) * 64 + c * 16);
      }

      // causal mask (only the diagonal tile)
      if (last) {
        const int qrel = l31 + (qb - jt * 64);  // 0..31 (qt even) or 32..63 (qt odd)
        const int h4 = hi * 4;
#pragma unroll
        for (int r = 0; r < 16; ++r) {
          const int kp = (r & 3) + ((r >> 2) << 3) + h4;
          s0[r] = (kp <= qrel) ? s0[r] : -1e30f;
          s1[r] = (kp + 32 <= qrel) ? s1[r] : -1e30f;
        }
      }

      // ---- in-register online softmax (per lane = one q-row's 32 kpos) ----
      float t8[8];
#pragma unroll
      for (int r = 0; r < 8; ++r)
        t8[r] = fmaxf(fmaxf(s0[r], s0[r + 8]), fmaxf(s1[r], s1[r + 8]));
      float tm = fmaxf(fmaxf(fmaxf(t8[0], t8[1]), fmaxf(t8[2], t8[3])),
                       fmaxf(fmaxf(t8[4], t8[5]), fmaxf(t8[6], t8[7])));
      tm = fmaxf(tm, __shfl_xor(tm, 32));
      if (!__all(tm <= mrun)) {
        const float mnew = fmaxf(mrun, tm);
        const float al = fast_exp2((mrun - mnew) * SC);
        mrun = mnew;
        lrun *= al;
#pragma unroll
        for (int r = 0; r < 16; ++r) { o0[r] *= al; o1[r] *= al; }
      }
      const float nb = -mrun * SC;
#pragma unroll
      for (int r = 0; r < 16; ++r) {
        s0[r] = fast_exp2(fmaf(s0[r], SC, nb));
        s1[r] = fast_exp2(fmaf(s1[r], SC, nb));
      }
      float u8[8];
#pragma unroll
      for (int r = 0; r < 8; ++r)
        u8[r] = (s0[r] + s0[r + 8]) + (s1[r] + s1[r + 8]);
      lrun += ((u8[0] + u8[1]) + (u8[2] + u8[3])) + ((u8[4] + u8[5]) + (u8[6] + u8[7]));

      // ---- pack P to bf16 B-fragments (cvt_pk + permlane32_swap, T12) ----
      bf16x8 pb0, pb1, pb2, pb3;
#define PACK_CHUNK(sv, bb, dst)                                   \
      {                                                           \
        u32 a0 = cvtpk(sv[bb + 0], sv[bb + 1]);                   \
        u32 a1 = cvtpk(sv[bb + 2], sv[bb + 3]);                   \
        u32 a2 = cvtpk(sv[bb + 4], sv[bb + 5]);                   \
        u32 a3 = cvtpk(sv[bb + 6], sv[bb + 7]);                   \
        plswap(a0, a2);                                           \
        plswap(a1, a3);                                           \
        u32x4 fv = {a0, a1, a2, a3};                              \
        dst = __builtin_bit_cast(bf16x8, fv);                     \
      }
      PACK_CHUNK(s0, 0, pb0)
      PACK_CHUNK(s0, 8, pb1)
      PACK_CHUNK(s1, 0, pb2)
      PACK_CHUNK(s1, 8, pb3)
#undef PACK_CHUNK

      // ---- O^T[d][q] += V^T . P^T ----
      o0 = __builtin_amdgcn_mfma_f32_32x32x16_bf16(vf[0][0], pb0, o0, 0, 0, 0);
      o1 = __builtin_amdgcn_mfma_f32_32x32x16_bf16(vf[1][0], pb0, o1, 0, 0, 0);
      o0 = __builtin_amdgcn_mfma_f32_32x32x16_bf16(vf[0][1], pb1, o0, 0, 0, 0);
      o1 = __builtin_amdgcn_mfma_f32_32x32x16_bf16(vf[1][1], pb1, o1, 0, 0, 0);
      o0 = __builtin_amdgcn_mfma_f32_32x32x16_bf16(vf[0][2], pb2, o0, 0, 0, 0);
      o1 = __builtin_amdgcn_mfma_f32_32x32x16_bf16(vf[1][2], pb2, o1, 0, 0, 0);
      o0 = __builtin_amdgcn_mfma_f32_32x32x16_bf16(vf[0][3], pb3, o0, 0, 0, 0);
      o1 = __builtin_amdgcn_mfma_f32_32x32x16_bf16(vf[1][3], pb3, o1, 0, 0, 0);
    }

    // ---- epilogue: combine partner row-sums, normalize, store bf16 ----
    const float lt = lrun + __shfl_xor(lrun, 32);
    const float inv = 1.0f / lt;
    u16* aorow = AO + (size_t)(b * 2048 + qb + l31) * 1024 + h * 64 + hi * 4;
#pragma unroll
    for (int g = 0; g < 4; ++g) {
      u32 w0 = cvtpk(o0[4 * g + 0] * inv, o0[4 * g + 1] * inv);
      u32 w1 = cvtpk(o0[4 * g + 2] * inv, o0[4 * g + 3] * inv);
      u32x2 ww = {w0, w1};
      *(u32x2*)(aorow + g * 8) = ww;
    }
#pragma unroll
    for (int g = 0; g < 4; ++g) {
      u32 w0 = cvtpk(o1[4 * g + 0] * inv, o1[4 * g + 1] * inv);
      u32 w1 = cvtpk(o1[4 * g + 2] * inv, o1[4 * g + 3] * inv);
      u32x2 ww = {w0, w1};
      *(u32x2*)(aorow + 32 + g * 8) = ww;
    }
  }
}

extern "C" void kernel_launch(void* const* d_in, const int* in_sizes, int n_in,
                              void* d_out, int out_size, void* d_ws, size_t ws_size,
                              hipStream_t stream) {
  const float* x      = (const float*)d_in[0];
  const float* w_attn = (const float*)d_in[1];
  const float* b_attn = (const float*)d_in[2];
  const float* w_proj = (const float*)d_in[3];
  const float* b_proj = (const float*)d_in[4];
  float* out = (float*)d_out;

  char* ws = (char*)d_ws;
  u16* x_bf  = (u16*)(ws);                    // [4096][1024] bf16   (8 MB)
  u16* wat_t = (u16*)(ws + 8388608);          // [3072][1024] bf16   (6 MB)
  u16* wpj_t = (u16*)(ws + 14680064);         // [1024][1024] bf16   (2 MB)
  u16* q_ws  = (u16*)(ws + 16777216);         // [B,H,S,d] bf16      (8 MB)
  u16* k_ws  = (u16*)(ws + 25165824);         // [B,H,S,d] bf16      (8 MB)
  u16* vT_ws = (u16*)(ws + 33554432);         // [B,H,d,S] bf16      (8 MB)
  u16* a_ws  = (u16*)(ws + 41943040);         // [B,S,nx]  bf16      (8 MB)

  k_cvt<<<4096, 256, 0, stream>>>(x, x_bf, 4194304);
  k_tcvt<<<dim3(96, 32), dim3(32, 8), 0, stream>>>(w_attn, wat_t, 1024, 3072);
  k_tcvt<<<dim3(32, 32), dim3(32, 8), 0, stream>>>(w_proj, wpj_t, 1024, 1024);

  k_gemm<0><<<dim3(24, 32), 256, 0, stream>>>(x_bf, wat_t, b_attn,
                                              q_ws, k_ws, vT_ws,
                                              out + 4194304, out + 8388608, nullptr);

  k_attn<<<dim3(256), 256, 0, stream>>>(q_ws, k_ws, vT_ws, a_ws);

  k_gemm<1><<<dim3(8, 32), 256, 0, stream>>>(a_ws, wpj_t, b_proj,
                                             nullptr, nullptr, nullptr,
                                             nullptr, nullptr, out);
}